// Round 9
// baseline (219.435 us; speedup 1.0000x reference)
//
#include <hip/hip_runtime.h>

#define LN_EPS 1e-5f

// ---------------------------------------------------------------------------
// ws layout (floats)
// ---------------------------------------------------------------------------
constexpr int T1_OFF   = 0;                       // 64*128*128 = 1048576
constexpr int WT2_OFF  = 1048576;                 // 25*4096  [k][rg][j][r]
constexpr int WT3_OFF  = WT2_OFF + 102400;        // 25*4096
constexpr int WT4_OFF  = WT3_OFF + 102400;        // 9*1024   [k][pos]
constexpr int WT5_OFF  = WT4_OFF + 9216;          // 9*1024
constexpr int WT6_OFF  = WT5_OFF + 9216;          // 9*256
constexpr int FCWT_OFF = WT6_OFF + 2304;          // [kq][row] float4 = 262144 floats

constexpr int NREP = 136;   // repack blocks prepended to the s1 grid

// ---------------------------------------------------------------------------
// K1: blocks [0,NREP): repack weights (contiguous reads, scattered writes —
// r7's proven direction). blocks [NREP,NREP+1024): stage-1 conv.
// ---------------------------------------------------------------------------
__global__ __launch_bounds__(256) void s1_conv(const float* __restrict__ x,
                                               const float* __restrict__ w1,
                                               const float* __restrict__ b1,
                                               const float* __restrict__ w2,
                                               const float* __restrict__ w3,
                                               const float* __restrict__ w4,
                                               const float* __restrict__ w5,
                                               const float* __restrict__ w6,
                                               const float* __restrict__ fcw,
                                               float* __restrict__ ws)
{
    const int tid = threadIdx.x;

    if (blockIdx.x < NREP) {
        const int rb = blockIdx.x;
        if (rb < 32) {              // w2 -> wT2 [k][rg][j][r]; read contiguous
            for (int idx = rb * 256 + tid; idx < 102400; idx += 32 * 256) {
                int p = idx / 25, k = idx % 25;       // p = i*64+j
                int i = p >> 6, j = p & 63;
                int rg = i >> 2, r = i & 3;
                ws[WT2_OFF + k * 4096 + rg * 256 + j * 4 + r] = w2[idx];
            }
        } else if (rb < 64) {       // w3 -> wT3
            for (int idx = (rb - 32) * 256 + tid; idx < 102400; idx += 32 * 256) {
                int p = idx / 25, k = idx % 25;
                int i = p >> 6, j = p & 63;
                int rg = i >> 2, r = i & 3;
                ws[WT3_OFF + k * 4096 + rg * 256 + j * 4 + r] = w3[idx];
            }
        } else if (rb < 68) {       // w4 -> wT4  [9][1024]
            for (int idx = (rb - 64) * 256 + tid; idx < 9216; idx += 4 * 256) {
                int p = idx / 9, k = idx % 9;
                ws[WT4_OFF + k * 1024 + p] = w4[idx];
            }
        } else if (rb < 72) {       // w5 -> wT5
            for (int idx = (rb - 68) * 256 + tid; idx < 9216; idx += 4 * 256) {
                int p = idx / 9, k = idx % 9;
                ws[WT5_OFF + k * 1024 + p] = w5[idx];
            }
        } else if (rb < 73) {       // w6 -> wT6  [9][256]
            for (int idx = tid; idx < 2304; idx += 256) {
                int p = idx / 9, k = idx % 9;
                ws[WT6_OFF + k * 256 + p] = w6[idx];
            }
        } else {                    // fcw [1024,256] -> fcwT4 [kq][row][4]
            for (int idx = (rb - 73) * 256 + tid; idx < 262144; idx += 63 * 256) {
                int r = idx >> 8, kc = idx & 255;
                int kq = kc >> 2, c = kc & 3;
                ws[FCWT_OFF + kq * 4096 + r * 4 + c] = fcw[idx];
            }
        }
        return;
    }

    // ---- stage-1 conv: 8x8 tile x 16 samples ----
    constexpr int R = 128, K = 7, TILE = 8, S = 16, PAD = 3;
    constexpr int RT = TILE + K - 1;
    constexpr int PP = RT * RT + 1;
    constexpr int NBLK = R / TILE;
    constexpr int WCNT = TILE * TILE * K * K;
    constexpr int PG = 256 / S;
    constexpr int OPT = TILE * TILE / PG;

    __shared__ float s_in[S * PP];
    __shared__ float s_w[WCNT];
    __shared__ float s_b[TILE * TILE];

    float* t1 = ws + T1_OFF;
    const int cb = blockIdx.x - NREP;
    const int bt = cb % (NBLK * NBLK);
    const int sg = cb / (NBLK * NBLK);
    const int i0 = (bt / NBLK) * TILE;
    const int j0 = (bt % NBLK) * TILE;
    const int S0 = sg * S;

    for (int idx = tid; idx < WCNT; idx += 256) {
        int pi = idx / (K * K), kk = idx % (K * K);
        int gi = i0 + pi / TILE, gj = j0 + pi % TILE;
        s_w[idx] = w1[(gi * R + gj) * (K * K) + kk];
    }
    if (tid < TILE * TILE)
        s_b[tid] = b1[(i0 + tid / TILE) * R + (j0 + tid % TILE)];

    for (int idx = tid; idx < S * RT * RT; idx += 256) {
        int ls = idx / (RT * RT), p = idx % (RT * RT);
        int ci = i0 - PAD + p / RT, cj = j0 - PAD + p % RT;
        float v = 0.0f;
        if (ci >= 0 && ci < R && cj >= 0 && cj < R)
            v = x[(S0 + ls) * R * R + ci * R + cj];
        s_in[ls * PP + p] = v;
    }
    __syncthreads();

    const int s = tid % S;
    const int pg = tid / S;
    const int p0 = pg * OPT;
    const int ti = p0 / TILE, tj0 = p0 % TILE;
    float acc[OPT];
    #pragma unroll
    for (int o = 0; o < OPT; o++) acc[o] = s_b[p0 + o];
    #pragma unroll
    for (int ki = 0; ki < K; ki++) {
        float row[OPT + K - 1];
        #pragma unroll
        for (int c = 0; c < OPT + K - 1; c++)
            row[c] = s_in[s * PP + (ti + ki) * RT + tj0 + c];
        #pragma unroll
        for (int kj = 0; kj < K; kj++)
            #pragma unroll
            for (int o = 0; o < OPT; o++)
                acc[o] += row[o + kj] * s_w[(p0 + o) * (K * K) + ki * K + kj];
    }
    #pragma unroll
    for (int o = 0; o < OPT; o++)
        t1[(S0 + s) * R * R + (i0 + ti) * R + (j0 + tj0 + o)] = fmaxf(acc[o], 0.0f);
}

// ---------------------------------------------------------------------------
// K2 — NT = 1024 threads, one block per sample.
// ---------------------------------------------------------------------------
constexpr int NT = 1024;
constexpr int NW = NT / 64;

__device__ __forceinline__ void stats_reduce(float* red, float lsum, float lsq,
                                             float inv_n, float* s_mu, float* s_rs)
{
    const int tid = threadIdx.x;
    #pragma unroll
    for (int off = 32; off > 0; off >>= 1) {
        lsum += __shfl_down(lsum, off, 64);
        lsq  += __shfl_down(lsq,  off, 64);
    }
    if ((tid & 63) == 0) { red[tid >> 6] = lsum; red[NW + (tid >> 6)] = lsq; }
    __syncthreads();
    if (tid == 0) {
        float a = 0.f, b = 0.f;
        #pragma unroll
        for (int i = 0; i < NW; i++) { a += red[i]; b += red[NW + i]; }
        float mu = a * inv_n, ms = b * inv_n;
        *s_mu = mu;
        *s_rs = rsqrtf(ms - mu * mu + LN_EPS);
    }
    __syncthreads();
}

// conv 5x5 over 64x64 (stride 68), column-strip: thread = (col j, rows 4rg..4rg+3).
// Lane-consecutive cols -> conflict-free LDS scalars + coalesced float4 weights.
__device__ __forceinline__ void conv64_5(const float* __restrict__ I,
                                         const float* __restrict__ wT,
                                         const float* __restrict__ bias,
                                         float* __restrict__ R,
                                         float& lsum, float& lsq)
{
    const int tid = threadIdx.x;
    const int j  = tid & 63;
    const int rg = tid >> 6;           // 0..15
    const int r0 = rg << 2;
    float a0 = bias[(r0 + 0) * 64 + j];
    float a1 = bias[(r0 + 1) * 64 + j];
    float a2 = bias[(r0 + 2) * 64 + j];
    float a3 = bias[(r0 + 3) * 64 + j];
    #pragma unroll
    for (int ki = 0; ki < 5; ki++) {
        const int i0 = r0 - 2 + ki;
        #pragma unroll
        for (int kj = 0; kj < 5; kj++) {
            float4 wv = *(const float4*)(wT + (ki * 5 + kj) * 4096 + rg * 256 + j * 4);
            int jj = j - 2 + kj;
            bool cok = (jj >= 0 && jj < 64);
            float v0 = (cok && i0 + 0 >= 0 && i0 + 0 < 64) ? I[(i0 + 0) * 68 + jj] : 0.f;
            float v1 = (cok && i0 + 1 >= 0 && i0 + 1 < 64) ? I[(i0 + 1) * 68 + jj] : 0.f;
            float v2 = (cok && i0 + 2 >= 0 && i0 + 2 < 64) ? I[(i0 + 2) * 68 + jj] : 0.f;
            float v3 = (cok && i0 + 3 >= 0 && i0 + 3 < 64) ? I[(i0 + 3) * 68 + jj] : 0.f;
            a0 += v0 * wv.x; a1 += v1 * wv.y; a2 += v2 * wv.z; a3 += v3 * wv.w;
        }
    }
    a0 = fmaxf(a0, 0.f); a1 = fmaxf(a1, 0.f);
    a2 = fmaxf(a2, 0.f); a3 = fmaxf(a3, 0.f);
    R[(r0 + 0) * 68 + j] = a0;
    R[(r0 + 1) * 68 + j] = a1;
    R[(r0 + 2) * 68 + j] = a2;
    R[(r0 + 3) * 68 + j] = a3;
    lsum += a0 + a1 + a2 + a3;
    lsq  += a0 * a0 + a1 * a1 + a2 * a2 + a3 * a3;
}

// conv 3x3 over 32x32 (stride 36). One position per thread.
__device__ __forceinline__ void conv32_3(const float* __restrict__ I,
                                         const float* __restrict__ wT,
                                         const float* __restrict__ bias,
                                         float* __restrict__ R,
                                         float& lsum, float& lsq)
{
    const int tid = threadIdx.x;
    const int i = tid >> 5, j = tid & 31;
    float acc = bias[tid];
    #pragma unroll
    for (int ki = 0; ki < 3; ki++) {
        int ii = i - 1 + ki;
        bool rok = (ii >= 0 && ii < 32);
        float r0 = (rok && j >= 1)  ? I[ii * 36 + j - 1] : 0.f;
        float r1 = rok              ? I[ii * 36 + j]     : 0.f;
        float r2 = (rok && j <= 30) ? I[ii * 36 + j + 1] : 0.f;
        acc += r0 * wT[(ki * 3 + 0) * 1024 + tid]
             + r1 * wT[(ki * 3 + 1) * 1024 + tid]
             + r2 * wT[(ki * 3 + 2) * 1024 + tid];
    }
    float v = fmaxf(acc, 0.f);
    R[i * 36 + j] = v;
    lsum += v; lsq += v * v;
}

// conv 3x3 over 16x16 (stride 20). Threads < 256 active.
__device__ __forceinline__ void conv16_3(const float* __restrict__ I,
                                         const float* __restrict__ wT,
                                         const float* __restrict__ bias,
                                         float* __restrict__ R,
                                         float& lsum, float& lsq)
{
    const int tid = threadIdx.x;
    if (tid >= 256) return;
    const int i = tid >> 4, j = tid & 15;
    float acc = bias[tid];
    #pragma unroll
    for (int ki = 0; ki < 3; ki++) {
        int ii = i - 1 + ki;
        bool rok = (ii >= 0 && ii < 16);
        float r0 = (rok && j >= 1)  ? I[ii * 20 + j - 1] : 0.f;
        float r1 = rok              ? I[ii * 20 + j]     : 0.f;
        float r2 = (rok && j <= 14) ? I[ii * 20 + j + 1] : 0.f;
        acc += r0 * wT[(ki * 3 + 0) * 256 + tid]
             + r1 * wT[(ki * 3 + 1) * 256 + tid]
             + r2 * wT[(ki * 3 + 2) * 256 + tid];
    }
    float v = fmaxf(acc, 0.f);
    R[i * 20 + j] = v;
    lsum += v; lsq += v * v;
}

// LN over 64-map, lane-consecutive scalar (conflict-free).
__device__ __forceinline__ void t64(const float* __restrict__ R, float mu, float rs,
                                    const float* __restrict__ g,
                                    const float* __restrict__ b,
                                    float* __restrict__ I)
{
    const int tid = threadIdx.x;
    #pragma unroll
    for (int o = 0; o < 4; o++) {
        int p = tid + o * NT;
        int i = p >> 6, j = p & 63;
        I[i * 68 + j] = (R[i * 68 + j] - mu) * rs * g[p] + b[p];
    }
}

// LN + 2x2 pool: 64-map (stride 68) -> 32-map I (stride 36).
__device__ __forceinline__ void t64pool(const float* __restrict__ R, float mu, float rs,
                                        const float* __restrict__ g,
                                        const float* __restrict__ b,
                                        float* __restrict__ I)
{
    const int tid = threadIdx.x;
    const int i = tid >> 5, j = tid & 31;
    float2 r0 = *((const float2*)(R + (2 * i) * 68 + 2 * j));
    float2 r1 = *((const float2*)(R + (2 * i + 1) * 68 + 2 * j));
    float2 g0 = *((const float2*)(g + (2 * i) * 64 + 2 * j));
    float2 g1 = *((const float2*)(g + (2 * i + 1) * 64 + 2 * j));
    float2 b0 = *((const float2*)(b + (2 * i) * 64 + 2 * j));
    float2 b1 = *((const float2*)(b + (2 * i + 1) * 64 + 2 * j));
    float n00 = (r0.x - mu) * rs * g0.x + b0.x;
    float n01 = (r0.y - mu) * rs * g0.y + b0.y;
    float n10 = (r1.x - mu) * rs * g1.x + b1.x;
    float n11 = (r1.y - mu) * rs * g1.y + b1.y;
    I[i * 36 + j] = fmaxf(fmaxf(n00, n01), fmaxf(n10, n11));
}

// LN over 32-map (stride 36).
__device__ __forceinline__ void t32(const float* __restrict__ R, float mu, float rs,
                                    const float* __restrict__ g,
                                    const float* __restrict__ b,
                                    float* __restrict__ I)
{
    const int tid = threadIdx.x;
    const int i = tid >> 5, j = tid & 31;
    I[i * 36 + j] = (R[i * 36 + j] - mu) * rs * g[tid] + b[tid];
}

// LN + 2x2 pool: 32-map (stride 36) -> 16-map I (stride 20). Threads < 256.
__device__ __forceinline__ void t32pool(const float* __restrict__ R, float mu, float rs,
                                        const float* __restrict__ g,
                                        const float* __restrict__ b,
                                        float* __restrict__ I)
{
    const int tid = threadIdx.x;
    if (tid >= 256) return;
    const int i = tid >> 4, j = tid & 15;
    float2 r0 = *((const float2*)(R + (2 * i) * 36 + 2 * j));
    float2 r1 = *((const float2*)(R + (2 * i + 1) * 36 + 2 * j));
    float2 g0 = *((const float2*)(g + (2 * i) * 32 + 2 * j));
    float2 g1 = *((const float2*)(g + (2 * i + 1) * 32 + 2 * j));
    float2 b0 = *((const float2*)(b + (2 * i) * 32 + 2 * j));
    float2 b1 = *((const float2*)(b + (2 * i + 1) * 32 + 2 * j));
    float n00 = (r0.x - mu) * rs * g0.x + b0.x;
    float n01 = (r0.y - mu) * rs * g0.y + b0.y;
    float n10 = (r1.x - mu) * rs * g1.x + b1.x;
    float n11 = (r1.y - mu) * rs * g1.y + b1.y;
    I[i * 20 + j] = fmaxf(fmaxf(n00, n01), fmaxf(n10, n11));
}

// ---------------------------------------------------------------------------
// K2: stages 2-6 + FC + softmax. One block (1024 thr) per sample.
// ---------------------------------------------------------------------------
__global__ __launch_bounds__(1024) void tail_fused(
    const float* __restrict__ ws_ro,
    const float* __restrict__ g1, const float* __restrict__ be1,
    const float* __restrict__ b2,
    const float* __restrict__ g2, const float* __restrict__ be2,
    const float* __restrict__ b3,
    const float* __restrict__ g3, const float* __restrict__ be3,
    const float* __restrict__ b4,
    const float* __restrict__ g4, const float* __restrict__ be4,
    const float* __restrict__ b5,
    const float* __restrict__ g5, const float* __restrict__ be5,
    const float* __restrict__ b6,
    const float* __restrict__ g6, const float* __restrict__ be6,
    const float* __restrict__ fcb,
    float* __restrict__ outp)
{
    __shared__ __align__(16) float I[64 * 68];
    __shared__ __align__(16) float R[64 * 68];
    __shared__ __align__(16) float h[256];
    __shared__ float red[2 * NW];
    __shared__ float s_mu, s_rs;

    const int s = blockIdx.x;
    const int tid = threadIdx.x;
    const float* x1  = ws_ro + T1_OFF + s * 16384;
    const float* wT2 = ws_ro + WT2_OFF;
    const float* wT3 = ws_ro + WT3_OFF;
    const float* wT4 = ws_ro + WT4_OFF;
    const float* wT5 = ws_ro + WT5_OFF;
    const float* wT6 = ws_ro + WT6_OFF;
    const float* fcwT4 = ws_ro + FCWT_OFF;

    // LN1 stats over raw stage-1 output (float4)
    float ls = 0.f, lq = 0.f;
    {
        const float4* x4 = (const float4*)x1;
        #pragma unroll
        for (int i = tid; i < 4096; i += NT) {
            float4 v = x4[i];
            ls += v.x + v.y + v.z + v.w;
            lq += v.x * v.x + v.y * v.y + v.z * v.z + v.w * v.w;
        }
    }
    stats_reduce(red, ls, lq, 1.f / 16384.f, &s_mu, &s_rs);

    // pool(LN1(t1)) -> I (64x64, stride 68). Thread = one pooled output.
    {
        float mu = s_mu, rs = s_rs;
        #pragma unroll
        for (int o = 0; o < 4; o++) {
            int p = tid + o * NT;
            int i = p >> 6, j = p & 63;
            float2 xa = *((const float2*)(x1 + (2 * i) * 128 + 2 * j));
            float2 xb = *((const float2*)(x1 + (2 * i + 1) * 128 + 2 * j));
            float2 ga = *((const float2*)(g1 + (2 * i) * 128 + 2 * j));
            float2 gb = *((const float2*)(g1 + (2 * i + 1) * 128 + 2 * j));
            float2 ba = *((const float2*)(be1 + (2 * i) * 128 + 2 * j));
            float2 bb = *((const float2*)(be1 + (2 * i + 1) * 128 + 2 * j));
            float n0 = (xa.x - mu) * rs * ga.x + ba.x;
            float n1 = (xa.y - mu) * rs * ga.y + ba.y;
            float n2 = (xb.x - mu) * rs * gb.x + bb.x;
            float n3 = (xb.y - mu) * rs * gb.y + bb.y;
            I[i * 68 + j] = fmaxf(fmaxf(n0, n1), fmaxf(n2, n3));
        }
    }
    __syncthreads();

    // S2: conv5 (64) -> R, LN2
    ls = lq = 0.f; conv64_5(I, wT2, b2, R, ls, lq);
    stats_reduce(red, ls, lq, 1.f / 4096.f, &s_mu, &s_rs);
    t64(R, s_mu, s_rs, g2, be2, I);
    __syncthreads();

    // S3: conv5 (64) -> R, LN3, pool -> 32
    ls = lq = 0.f; conv64_5(I, wT3, b3, R, ls, lq);
    stats_reduce(red, ls, lq, 1.f / 4096.f, &s_mu, &s_rs);
    t64pool(R, s_mu, s_rs, g3, be3, I);
    __syncthreads();

    // S4: conv3 (32) -> R, LN4
    ls = lq = 0.f; conv32_3(I, wT4, b4, R, ls, lq);
    stats_reduce(red, ls, lq, 1.f / 1024.f, &s_mu, &s_rs);
    t32(R, s_mu, s_rs, g4, be4, I);
    __syncthreads();

    // S5: conv3 (32) -> R, LN5, pool -> 16
    ls = lq = 0.f; conv32_3(I, wT5, b5, R, ls, lq);
    stats_reduce(red, ls, lq, 1.f / 1024.f, &s_mu, &s_rs);
    t32pool(R, s_mu, s_rs, g5, be5, I);
    __syncthreads();

    // S6: conv3 (16) -> R, LN6
    ls = lq = 0.f; conv16_3(I, wT6, b6, R, ls, lq);
    stats_reduce(red, ls, lq, 1.f / 256.f, &s_mu, &s_rs);

    // LN6 -> h[256]
    if (tid < 256) {
        int i = tid >> 4, j = tid & 15;
        h[tid] = (R[i * 20 + j] - s_mu) * s_rs * g6[tid] + be6[tid];
    }
    __syncthreads();

    // FC 256->1024: one logit/thread, 64 coalesced float4 weight loads.
    float acc = fcb[tid];
    {
        const float4* wq = (const float4*)fcwT4;
        const float4* h4 = (const float4*)h;
        #pragma unroll 8
        for (int kq = 0; kq < 64; kq++) {
            float4 wv = wq[kq * 1024 + tid];
            float4 hv = h4[kq];
            acc += wv.x * hv.x + wv.y * hv.y + wv.z * hv.z + wv.w * hv.w;
        }
    }

    // softmax over the block's 1024 logits
    float m = acc;
    #pragma unroll
    for (int off = 32; off > 0; off >>= 1)
        m = fmaxf(m, __shfl_down(m, off, 64));
    if ((tid & 63) == 0) red[tid >> 6] = m;
    __syncthreads();
    if (tid == 0) {
        float mm = red[0];
        #pragma unroll
        for (int i = 1; i < NW; i++) mm = fmaxf(mm, red[i]);
        s_mu = mm;
    }
    __syncthreads();
    float e = expf(acc - s_mu);
    float sum = e;
    #pragma unroll
    for (int off = 32; off > 0; off >>= 1)
        sum += __shfl_down(sum, off, 64);
    if ((tid & 63) == 0) red[NW + (tid >> 6)] = sum;
    __syncthreads();
    if (tid == 0) {
        float ss = 0.f;
        #pragma unroll
        for (int i = 0; i < NW; i++) ss += red[NW + i];
        s_rs = 1.0f / ss;
    }
    __syncthreads();
    outp[s * 1024 + tid] = e * s_rs;
}

// ---------------------------------------------------------------------------
extern "C" void kernel_launch(void* const* d_in, const int* in_sizes, int n_in,
                              void* d_out, int out_size, void* d_ws, size_t ws_size,
                              hipStream_t stream) {
    (void)in_sizes; (void)n_in; (void)out_size; (void)ws_size;

    const float* x   = (const float*)d_in[0];
    const float* w1  = (const float*)d_in[1];  const float* b1  = (const float*)d_in[2];
    const float* g1  = (const float*)d_in[3];  const float* be1 = (const float*)d_in[4];
    const float* w2  = (const float*)d_in[5];  const float* b2  = (const float*)d_in[6];
    const float* g2  = (const float*)d_in[7];  const float* be2 = (const float*)d_in[8];
    const float* w3  = (const float*)d_in[9];  const float* b3  = (const float*)d_in[10];
    const float* g3  = (const float*)d_in[11]; const float* be3 = (const float*)d_in[12];
    const float* w4  = (const float*)d_in[13]; const float* b4  = (const float*)d_in[14];
    const float* g4  = (const float*)d_in[15]; const float* be4 = (const float*)d_in[16];
    const float* w5  = (const float*)d_in[17]; const float* b5  = (const float*)d_in[18];
    const float* g5  = (const float*)d_in[19]; const float* be5 = (const float*)d_in[20];
    const float* w6  = (const float*)d_in[21]; const float* b6  = (const float*)d_in[22];
    const float* g6  = (const float*)d_in[23]; const float* be6 = (const float*)d_in[24];
    const float* fcw = (const float*)d_in[25]; const float* fcb = (const float*)d_in[26];

    float* ws = (float*)d_ws;

    s1_conv<<<NREP + 1024, 256, 0, stream>>>(x, w1, b1, w2, w3, w4, w5, w6, fcw, ws);
    tail_fused<<<64, 1024, 0, stream>>>((const float*)ws,
        g1, be1, b2, g2, be2, b3, g3, be3,
        b4, g4, be4, b5, g5, be5, b6, g6, be6,
        fcb, (float*)d_out);
}

// Round 10
// 154.860 us; speedup vs baseline: 1.4170x; 1.4170x over previous
//
#include <hip/hip_runtime.h>

#define LN_EPS 1e-5f

// ---------------------------------------------------------------------------
// ws layout (floats)
// ---------------------------------------------------------------------------
constexpr int T1_OFF   = 0;                       // 64*128*128 = 1048576
constexpr int WT2_OFF  = 1048576;                 // 25*4096 [k][pos]
constexpr int WT3_OFF  = WT2_OFF + 102400;        // 25*4096
constexpr int WT4_OFF  = WT3_OFF + 102400;        // 9*1024
constexpr int WT5_OFF  = WT4_OFF + 9216;          // 9*1024
constexpr int WT6_OFF  = WT5_OFF + 9216;          // 9*256
constexpr int FCWT_OFF = WT6_OFF + 2304;          // [kq][row] float4 = 262144 floats

constexpr int NREP = 136;   // repack blocks prepended to the s1 grid

// ---------------------------------------------------------------------------
// K1: blocks [0,NREP): repack weights (contiguous reads, scattered writes).
//     blocks [NREP,NREP+1024): stage-1 LC conv 7x7 pad 3 -> raw ReLU t1.
// ---------------------------------------------------------------------------
__global__ __launch_bounds__(256) void s1_conv(const float* __restrict__ x,
                                               const float* __restrict__ w1,
                                               const float* __restrict__ b1,
                                               const float* __restrict__ w2,
                                               const float* __restrict__ w3,
                                               const float* __restrict__ w4,
                                               const float* __restrict__ w5,
                                               const float* __restrict__ w6,
                                               const float* __restrict__ fcw,
                                               float* __restrict__ ws)
{
    const int tid = threadIdx.x;

    if (blockIdx.x < NREP) {
        const int rb = blockIdx.x;
        if (rb < 32) {              // w2 -> wT2  [25][4096]
            for (int idx = rb * 256 + tid; idx < 102400; idx += 32 * 256) {
                int p = idx / 25, k = idx % 25;
                ws[WT2_OFF + k * 4096 + p] = w2[idx];
            }
        } else if (rb < 64) {       // w3 -> wT3
            for (int idx = (rb - 32) * 256 + tid; idx < 102400; idx += 32 * 256) {
                int p = idx / 25, k = idx % 25;
                ws[WT3_OFF + k * 4096 + p] = w3[idx];
            }
        } else if (rb < 68) {       // w4 -> wT4  [9][1024]
            for (int idx = (rb - 64) * 256 + tid; idx < 9216; idx += 4 * 256) {
                int p = idx / 9, k = idx % 9;
                ws[WT4_OFF + k * 1024 + p] = w4[idx];
            }
        } else if (rb < 72) {       // w5 -> wT5
            for (int idx = (rb - 68) * 256 + tid; idx < 9216; idx += 4 * 256) {
                int p = idx / 9, k = idx % 9;
                ws[WT5_OFF + k * 1024 + p] = w5[idx];
            }
        } else if (rb < 73) {       // w6 -> wT6  [9][256]
            for (int idx = tid; idx < 2304; idx += 256) {
                int p = idx / 9, k = idx % 9;
                ws[WT6_OFF + k * 256 + p] = w6[idx];
            }
        } else {                    // fcw [1024,256] -> fcwT4 [kq][row][4]
            for (int idx = (rb - 73) * 256 + tid; idx < 262144; idx += 63 * 256) {
                int r = idx >> 8, kc = idx & 255;
                int kq = kc >> 2, c = kc & 3;
                ws[FCWT_OFF + kq * 4096 + r * 4 + c] = fcw[idx];
            }
        }
        return;
    }

    // ---- stage-1 conv: 8x8 tile x 16 samples ----
    constexpr int R = 128, K = 7, TILE = 8, S = 16, PAD = 3;
    constexpr int RT = TILE + K - 1;
    constexpr int PP = RT * RT + 1;
    constexpr int NBLK = R / TILE;
    constexpr int WCNT = TILE * TILE * K * K;
    constexpr int PG = 256 / S;
    constexpr int OPT = TILE * TILE / PG;

    __shared__ float s_in[S * PP];
    __shared__ float s_w[WCNT];
    __shared__ float s_b[TILE * TILE];

    float* t1 = ws + T1_OFF;
    const int cb = blockIdx.x - NREP;
    const int bt = cb % (NBLK * NBLK);
    const int sg = cb / (NBLK * NBLK);
    const int i0 = (bt / NBLK) * TILE;
    const int j0 = (bt % NBLK) * TILE;
    const int S0 = sg * S;

    for (int idx = tid; idx < WCNT; idx += 256) {
        int pi = idx / (K * K), kk = idx % (K * K);
        int gi = i0 + pi / TILE, gj = j0 + pi % TILE;
        s_w[idx] = w1[(gi * R + gj) * (K * K) + kk];
    }
    if (tid < TILE * TILE)
        s_b[tid] = b1[(i0 + tid / TILE) * R + (j0 + tid % TILE)];

    for (int idx = tid; idx < S * RT * RT; idx += 256) {
        int ls = idx / (RT * RT), p = idx % (RT * RT);
        int ci = i0 - PAD + p / RT, cj = j0 - PAD + p % RT;
        float v = 0.0f;
        if (ci >= 0 && ci < R && cj >= 0 && cj < R)
            v = x[(S0 + ls) * R * R + ci * R + cj];
        s_in[ls * PP + p] = v;
    }
    __syncthreads();

    const int s = tid % S;
    const int pg = tid / S;
    const int p0 = pg * OPT;
    const int ti = p0 / TILE, tj0 = p0 % TILE;
    float acc[OPT];
    #pragma unroll
    for (int o = 0; o < OPT; o++) acc[o] = s_b[p0 + o];
    #pragma unroll
    for (int ki = 0; ki < K; ki++) {
        float row[OPT + K - 1];
        #pragma unroll
        for (int c = 0; c < OPT + K - 1; c++)
            row[c] = s_in[s * PP + (ti + ki) * RT + tj0 + c];
        #pragma unroll
        for (int kj = 0; kj < K; kj++)
            #pragma unroll
            for (int o = 0; o < OPT; o++)
                acc[o] += row[o + kj] * s_w[(p0 + o) * (K * K) + ki * K + kj];
    }
    #pragma unroll
    for (int o = 0; o < OPT; o++)
        t1[(S0 + s) * R * R + (i0 + ti) * R + (j0 + tj0 + o)] = fmaxf(acc[o], 0.0f);
}

// ---------------------------------------------------------------------------
// K2 — NT = 1024 threads, one block per sample. Odd LDS strides (65/33/17).
// ---------------------------------------------------------------------------
constexpr int NT = 1024;
constexpr int NW = NT / 64;

__device__ __forceinline__ void stats_reduce(float* red, float lsum, float lsq,
                                             float inv_n, float* s_mu, float* s_rs)
{
    const int tid = threadIdx.x;
    #pragma unroll
    for (int off = 32; off > 0; off >>= 1) {
        lsum += __shfl_down(lsum, off, 64);
        lsq  += __shfl_down(lsq,  off, 64);
    }
    if ((tid & 63) == 0) { red[tid >> 6] = lsum; red[NW + (tid >> 6)] = lsq; }
    __syncthreads();
    if (tid == 0) {
        float a = 0.f, b = 0.f;
        #pragma unroll
        for (int i = 0; i < NW; i++) { a += red[i]; b += red[NW + i]; }
        float mu = a * inv_n, ms = b * inv_n;
        *s_mu = mu;
        *s_rs = rsqrtf(ms - mu * mu + LN_EPS);
    }
    __syncthreads();
}

// conv KxK over M x M LDS map (stride M+1) -> ReLU into R, accumulating
// sum/sumsq. Weights [k][NPOS], lane-consecutive p -> coalesced reads.
template<int M, int K>
__device__ __forceinline__ void conv_lds(const float* __restrict__ I,
                                         const float* __restrict__ wT,
                                         const float* __restrict__ bias,
                                         float* __restrict__ R,
                                         float& lsum, float& lsq)
{
    constexpr int NPOS = M * M;
    constexpr int PADK = (K - 1) / 2;
    constexpr int STR = M + 1;
    constexpr int OPT = (NPOS + NT - 1) / NT;
    const int tid = threadIdx.x;

    #pragma unroll
    for (int o = 0; o < OPT; o++) {
        int p = tid + o * NT;
        if (NPOS < NT && p >= NPOS) break;
        int i = p / M, j = p % M;
        float acc = bias[p];
        #pragma unroll
        for (int ki = 0; ki < K; ki++) {
            int ii = i - PADK + ki;
            bool rok = (ii >= 0 && ii < M);
            #pragma unroll
            for (int kj = 0; kj < K; kj++) {
                int jj = j - PADK + kj;
                float iv = (rok && jj >= 0 && jj < M) ? I[ii * STR + jj] : 0.0f;
                acc += iv * wT[(ki * K + kj) * NPOS + p];
            }
        }
        float v = fmaxf(acc, 0.0f);
        R[i * STR + j] = v;
        lsum += v;
        lsq  += v * v;
    }
}

// LN (+ optional 2x2 maxpool) of raw map R (res N, stride N+1) -> I (res M).
template<int N, bool POOL>
__device__ __forceinline__ void transform(const float* __restrict__ R,
                                          float mu, float rs,
                                          const float* __restrict__ g,
                                          const float* __restrict__ b,
                                          float* __restrict__ I)
{
    constexpr int M = POOL ? N / 2 : N;
    constexpr int SR = N + 1, SI = M + 1;
    const int tid = threadIdx.x;
    for (int p = tid; p < M * M; p += NT) {
        int i = p / M, j = p % M;
        float v;
        if constexpr (POOL) {
            float best = -3.4e38f;
            #pragma unroll
            for (int dy = 0; dy < 2; dy++)
                #pragma unroll
                for (int dx = 0; dx < 2; dx++) {
                    int r = 2 * i + dy, c = 2 * j + dx;
                    float n = (R[r * SR + c] - mu) * rs * g[r * N + c] + b[r * N + c];
                    best = fmaxf(best, n);
                }
            v = best;
        } else {
            v = (R[i * SR + j] - mu) * rs * g[i * N + j] + b[i * N + j];
        }
        I[i * SI + j] = v;
    }
}

// ---------------------------------------------------------------------------
// K2: stages 2-6 + FC + softmax. One block (1024 thr) per sample.
// ---------------------------------------------------------------------------
__global__ __launch_bounds__(1024) void tail_fused(
    const float* __restrict__ ws_ro,
    const float* __restrict__ g1, const float* __restrict__ be1,
    const float* __restrict__ b2,
    const float* __restrict__ g2, const float* __restrict__ be2,
    const float* __restrict__ b3,
    const float* __restrict__ g3, const float* __restrict__ be3,
    const float* __restrict__ b4,
    const float* __restrict__ g4, const float* __restrict__ be4,
    const float* __restrict__ b5,
    const float* __restrict__ g5, const float* __restrict__ be5,
    const float* __restrict__ b6,
    const float* __restrict__ g6, const float* __restrict__ be6,
    const float* __restrict__ fcb,
    float* __restrict__ outp)
{
    __shared__ __align__(16) float I[64 * 65];
    __shared__ __align__(16) float R[64 * 65];
    __shared__ __align__(16) float h[256];
    __shared__ float red[2 * NW];
    __shared__ float s_mu, s_rs;

    const int s = blockIdx.x;
    const int tid = threadIdx.x;
    const float* x1  = ws_ro + T1_OFF + s * 16384;
    const float* wT2 = ws_ro + WT2_OFF;
    const float* wT3 = ws_ro + WT3_OFF;
    const float* wT4 = ws_ro + WT4_OFF;
    const float* wT5 = ws_ro + WT5_OFF;
    const float* wT6 = ws_ro + WT6_OFF;

    // LN1 stats over raw stage-1 output (float4)
    float ls = 0.f, lq = 0.f;
    {
        const float4* x4 = (const float4*)x1;
        #pragma unroll
        for (int i = tid; i < 4096; i += NT) {
            float4 v = x4[i];
            ls += v.x + v.y + v.z + v.w;
            lq += v.x * v.x + v.y * v.y + v.z * v.z + v.w * v.w;
        }
    }
    stats_reduce(red, ls, lq, 1.f / 16384.f, &s_mu, &s_rs);

    // pool(LN1(t1)) -> I (64x64, stride 65). float2 loads, lane-consecutive.
    {
        float mu = s_mu, rs = s_rs;
        #pragma unroll
        for (int o = 0; o < 4; o++) {
            int p = tid + o * NT;
            int i = p >> 6, j = p & 63;
            float2 xa = *((const float2*)(x1 + (2 * i) * 128 + 2 * j));
            float2 xb = *((const float2*)(x1 + (2 * i + 1) * 128 + 2 * j));
            float2 ga = *((const float2*)(g1 + (2 * i) * 128 + 2 * j));
            float2 gb = *((const float2*)(g1 + (2 * i + 1) * 128 + 2 * j));
            float2 ba = *((const float2*)(be1 + (2 * i) * 128 + 2 * j));
            float2 bb = *((const float2*)(be1 + (2 * i + 1) * 128 + 2 * j));
            float n0 = (xa.x - mu) * rs * ga.x + ba.x;
            float n1 = (xa.y - mu) * rs * ga.y + ba.y;
            float n2 = (xb.x - mu) * rs * gb.x + bb.x;
            float n3 = (xb.y - mu) * rs * gb.y + bb.y;
            I[i * 65 + j] = fmaxf(fmaxf(n0, n1), fmaxf(n2, n3));
        }
    }
    __syncthreads();

    // S2: conv5 -> R, LN2
    ls = lq = 0.f; conv_lds<64, 5>(I, wT2, b2, R, ls, lq);
    stats_reduce(red, ls, lq, 1.f / 4096.f, &s_mu, &s_rs);
    transform<64, false>(R, s_mu, s_rs, g2, be2, I);
    __syncthreads();

    // S3: conv5 -> R, LN3, pool -> 32
    ls = lq = 0.f; conv_lds<64, 5>(I, wT3, b3, R, ls, lq);
    stats_reduce(red, ls, lq, 1.f / 4096.f, &s_mu, &s_rs);
    transform<64, true>(R, s_mu, s_rs, g3, be3, I);
    __syncthreads();

    // S4: conv3 (32) -> R, LN4
    ls = lq = 0.f; conv_lds<32, 3>(I, wT4, b4, R, ls, lq);
    stats_reduce(red, ls, lq, 1.f / 1024.f, &s_mu, &s_rs);
    transform<32, false>(R, s_mu, s_rs, g4, be4, I);
    __syncthreads();

    // S5: conv3 (32) -> R, LN5, pool -> 16
    ls = lq = 0.f; conv_lds<32, 3>(I, wT5, b5, R, ls, lq);
    stats_reduce(red, ls, lq, 1.f / 1024.f, &s_mu, &s_rs);
    transform<32, true>(R, s_mu, s_rs, g5, be5, I);
    __syncthreads();

    // S6: conv3 (16) -> R, LN6
    ls = lq = 0.f; conv_lds<16, 3>(I, wT6, b6, R, ls, lq);
    stats_reduce(red, ls, lq, 1.f / 256.f, &s_mu, &s_rs);

    // LN6 -> h[256]
    if (tid < 256) {
        int i = tid >> 4, j = tid & 15;
        h[tid] = (R[i * 17 + j] - s_mu) * s_rs * g6[tid] + be6[tid];
    }
    __syncthreads();

    // FC 256->1024: one logit/thread, 64 coalesced float4 weight loads.
    float acc = fcb[tid];
    {
        const float4* wq = (const float4*)(ws_ro + FCWT_OFF);
        const float4* h4 = (const float4*)h;
        #pragma unroll 8
        for (int kq = 0; kq < 64; kq++) {
            float4 wv = wq[kq * 1024 + tid];
            float4 hv = h4[kq];
            acc += wv.x * hv.x + wv.y * hv.y + wv.z * hv.z + wv.w * hv.w;
        }
    }

    // softmax over the block's 1024 logits
    float m = acc;
    #pragma unroll
    for (int off = 32; off > 0; off >>= 1)
        m = fmaxf(m, __shfl_down(m, off, 64));
    if ((tid & 63) == 0) red[tid >> 6] = m;
    __syncthreads();
    if (tid == 0) {
        float mm = red[0];
        #pragma unroll
        for (int i = 1; i < NW; i++) mm = fmaxf(mm, red[i]);
        s_mu = mm;
    }
    __syncthreads();
    float e = expf(acc - s_mu);
    float sum = e;
    #pragma unroll
    for (int off = 32; off > 0; off >>= 1)
        sum += __shfl_down(sum, off, 64);
    if ((tid & 63) == 0) red[NW + (tid >> 6)] = sum;
    __syncthreads();
    if (tid == 0) {
        float ss = 0.f;
        #pragma unroll
        for (int i = 0; i < NW; i++) ss += red[NW + i];
        s_rs = 1.0f / ss;
    }
    __syncthreads();
    outp[s * 1024 + tid] = e * s_rs;
}

// ---------------------------------------------------------------------------
extern "C" void kernel_launch(void* const* d_in, const int* in_sizes, int n_in,
                              void* d_out, int out_size, void* d_ws, size_t ws_size,
                              hipStream_t stream) {
    (void)in_sizes; (void)n_in; (void)out_size; (void)ws_size;

    const float* x   = (const float*)d_in[0];
    const float* w1  = (const float*)d_in[1];  const float* b1  = (const float*)d_in[2];
    const float* g1  = (const float*)d_in[3];  const float* be1 = (const float*)d_in[4];
    const float* w2  = (const float*)d_in[5];  const float* b2  = (const float*)d_in[6];
    const float* g2  = (const float*)d_in[7];  const float* be2 = (const float*)d_in[8];
    const float* w3  = (const float*)d_in[9];  const float* b3  = (const float*)d_in[10];
    const float* g3  = (const float*)d_in[11]; const float* be3 = (const float*)d_in[12];
    const float* w4  = (const float*)d_in[13]; const float* b4  = (const float*)d_in[14];
    const float* g4  = (const float*)d_in[15]; const float* be4 = (const float*)d_in[16];
    const float* w5  = (const float*)d_in[17]; const float* b5  = (const float*)d_in[18];
    const float* g5  = (const float*)d_in[19]; const float* be5 = (const float*)d_in[20];
    const float* w6  = (const float*)d_in[21]; const float* b6  = (const float*)d_in[22];
    const float* g6  = (const float*)d_in[23]; const float* be6 = (const float*)d_in[24];
    const float* fcw = (const float*)d_in[25]; const float* fcb = (const float*)d_in[26];

    float* ws = (float*)d_ws;

    s1_conv<<<NREP + 1024, 256, 0, stream>>>(x, w1, b1, w2, w3, w4, w5, w6, fcw, ws);
    tail_fused<<<64, 1024, 0, stream>>>((const float*)ws,
        g1, be1, b2, g2, be2, b3, g3, be3,
        b4, g4, be4, b5, g5, be5, b6, g6, be6,
        fcb, (float*)d_out);
}